// Round 8
// baseline (108.483 us; speedup 1.0000x reference)
//
#include <hip/hip_runtime.h>
#include <math.h>

#define PIX 4096
typedef unsigned short ushort_t;
typedef unsigned int uint_t;
typedef __attribute__((ext_vector_type(8))) short bf16x8;
typedef __attribute__((ext_vector_type(16))) float f32x16;

// ---- ws layout (floats) ----
//   qkvB  [128][4096]           @ 0         (k ch 0..63, v ch 64..127)
//   APart [16ks][4h][4096][17]  @ 524288    (cols 0-15 = PV partial, col16 = den partial)
// ushort region @ float offset 4980736:
//   QH [4][4096][16] @0   QL @262144
//   KF [4][288][1024] @524288            (per chunk: 512 hi + 512 lo, lane-frag order)
//   VF [4][288][512]  @1703936           (per chunk: 2 halves x 256, hi only, frag order)
#define OFF_APART 524288
#define OFF_USHORT 4980736
#define U_QH 0
#define U_QL 262144
#define U_KF 524288
#define U_VF 1703936

#define QSCALE 0.36067376022224087f   // 0.25 * log2(e)

#if defined(__has_builtin)
#if __has_builtin(__builtin_amdgcn_exp2f)
#define EXP2F(x) __builtin_amdgcn_exp2f(x)
#endif
#if __has_builtin(__builtin_amdgcn_perm)
#define PKHI16(u1, u0) __builtin_amdgcn_perm((u1), (u0), 0x07060302u)
#endif
#endif
#ifndef EXP2F
#define EXP2F(x) exp2f(x)
#endif
#ifndef PKHI16
#define PKHI16(u1, u0) (((u0) >> 16) | ((u1) & 0xFFFF0000u))
#endif

__device__ __forceinline__ void split_trunc(float x, ushort_t& hb, ushort_t& lb) {
    uint_t u = __float_as_uint(x);
    uint_t t = u & 0xFFFF0000u;
    float lo = x - __uint_as_float(t);
    hb = (ushort_t)(u >> 16);
    lb = (ushort_t)(__float_as_uint(lo) >> 16);
}

__device__ __forceinline__ void split8(const float* v, bf16x8& H, bf16x8& L) {
    union { uint_t u[4]; bf16x8 b; } hh, ll;
    #pragma unroll
    for (int j = 0; j < 4; ++j) {
        uint_t u0 = __float_as_uint(v[2 * j]), u1 = __float_as_uint(v[2 * j + 1]);
        hh.u[j] = PKHI16(u1, u0);
        float l0 = v[2 * j]     - __uint_as_float(u0 & 0xFFFF0000u);
        float l1 = v[2 * j + 1] - __uint_as_float(u1 & 0xFFFF0000u);
        ll.u[j] = PKHI16(__float_as_uint(l1), __float_as_uint(l0));
    }
    H = hh.b; L = ll.b;
}

// ---------------- K1: fused norm + qkv MFMA projection (unchanged, verified) ----------------
__global__ __launch_bounds__(256)
void k_nq(const float* __restrict__ x, const float* __restrict__ w_qkv,
          const float* __restrict__ ln_w, float* __restrict__ qkvB,
          ushort_t* __restrict__ QH, ushort_t* __restrict__ QL)
{
    __shared__ float xs[64 * 32];
    __shared__ float red[2][8][32];
    __shared__ float rstd_s[32];
    __shared__ float lw[64];
    __shared__ ushort_t xh[32 * 64];
    __shared__ ushort_t xl[32 * 64];

    const int tid = threadIdx.x;
    const int px = tid & 31, cg = tid >> 5;
    const int pbase = ((int)blockIdx.x >> 1) * 32;
    const int ohalf = blockIdx.x & 1;

    if (tid < 64) lw[tid] = ln_w[tid];
    float s = 0.f, s2 = 0.f;
    #pragma unroll
    for (int cl = 0; cl < 8; ++cl) {
        int c = cg * 8 + cl;
        float v = x[c * PIX + pbase + px];
        xs[c * 32 + px] = v;
        s += v; s2 = fmaf(v, v, s2);
    }
    red[0][cg][px] = s; red[1][cg][px] = s2;
    __syncthreads();
    if (tid < 32) {
        float a = 0.f, b = 0.f;
        #pragma unroll
        for (int gidx = 0; gidx < 8; ++gidx) { a += red[0][gidx][tid]; b += red[1][gidx][tid]; }
        float mean = a * 0.015625f;
        float var  = fmaf(-mean, mean, b * 0.015625f);
        rstd_s[tid] = 1.0f / sqrtf(var + 1e-5f);
    }
    __syncthreads();
    {
        float vals[8];
        const float r = rstd_s[px];
        #pragma unroll
        for (int cl = 0; cl < 8; ++cl) {
            int c = cg * 8 + cl;
            vals[cl] = xs[c * 32 + px] * r * lw[c];
        }
        bf16x8 H, L; split8(vals, H, L);
        const int g = cg ^ (px & 7);
        *(bf16x8*)&xh[px * 64 + g * 8] = H;
        *(bf16x8*)&xl[px * 64 + g * 8] = L;
    }
    __syncthreads();

    const int w = tid >> 6;
    if (w >= 3) return;
    const int l = tid & 63, col = l & 31, rl = l >> 5;
    const int obase = ohalf * 96 + w * 32;

    bf16x8 wh[4], wl[4], xhf[4], xlf[4];
    const float* wrow = w_qkv + (obase + col) * 64;
    #pragma unroll
    for (int s4 = 0; s4 < 4; ++s4) {
        float tmp[8];
        *(float4*)&tmp[0] = *(const float4*)&wrow[s4 * 16 + rl * 8];
        *(float4*)&tmp[4] = *(const float4*)&wrow[s4 * 16 + rl * 8 + 4];
        split8(tmp, wh[s4], wl[s4]);
        const int g = (s4 * 2 + rl) ^ (col & 7);
        xhf[s4] = *(const bf16x8*)&xh[col * 64 + g * 8];
        xlf[s4] = *(const bf16x8*)&xl[col * 64 + g * 8];
    }
    f32x16 acc = {0,0,0,0,0,0,0,0,0,0,0,0,0,0,0,0};
    #pragma unroll
    for (int s4 = 0; s4 < 4; ++s4) {
        acc = __builtin_amdgcn_mfma_f32_32x32x16_bf16(wh[s4], xhf[s4], acc, 0, 0, 0);
        acc = __builtin_amdgcn_mfma_f32_32x32x16_bf16(wl[s4], xhf[s4], acc, 0, 0, 0);
        acc = __builtin_amdgcn_mfma_f32_32x32x16_bf16(wh[s4], xlf[s4], acc, 0, 0, 0);
    }
    const int gpx = pbase + col;
    #pragma unroll
    for (int j = 0; j < 16; ++j) {
        const int o = obase + (j & 3) + 8 * (j >> 2) + 4 * rl;
        if (o < 64) {
            float qv = acc[j] * QSCALE;
            ushort_t hb, lb; split_trunc(qv, hb, lb);
            const int a = ((o >> 4) * PIX + gpx) * 16 + (o & 15);
            QH[a] = hb; QL[a] = lb;
        } else {
            qkvB[(o - 64) * PIX + gpx] = acc[j];
        }
    }
}

// ---------------- K2: K (hi/lo) + V (hi) unfold-gather, 8 elems/thread ----------------
__global__ __launch_bounds__(256)
void k_prep_kv(const float* __restrict__ qkvB,
               ushort_t* __restrict__ KF, ushort_t* __restrict__ VF)
{
    const int bid = blockIdx.x;
    const int tid = threadIdx.x;
    if (bid < 288) {
        const int t = bid * 256 + tid;          // < 73728
        const int h = t / 18432; int r = t - h * 18432;
        const int i = r >> 6;   const int l = r & 63;
        const int col = l & 31, rl = l >> 5;
        const int m = i * 32 + col;
        const int cc = m / 576;  const int r3 = m - cc * 576;
        const int orr = r3 / 48; const int r4 = r3 - orr * 48;
        const int oc = r4 >> 2, wg = r4 & 3;
        const int row = wg * 16 + rl * 8 + orr - 2;
        const bool rowOk = (unsigned)row < 64u;
        const float* src = qkvB + (h * 16 + cc) * PIX + row * 64 + (oc - 2);
        float vals[8];
        #pragma unroll
        for (int j = 0; j < 8; ++j) {
            const int colp = j * 8 + oc - 2;
            vals[j] = (rowOk && (unsigned)colp < 64u) ? src[j * 8] : 0.f;
        }
        bf16x8 H, L; split8(vals, H, L);
        const int base = (h * 288 + i) * 1024 + l * 8;
        *(bf16x8*)&KF[base]       = H;
        *(bf16x8*)&KF[base + 512] = L;
    } else {
        const int t = (bid - 288) * 256 + tid;  // < 73728
        const int h = t / 18432; int r = t - h * 18432;
        const int i = r >> 6;   const int r2 = r & 63;
        const int half = r2 >> 5; const int rl = (r2 >> 4) & 1; const int colD = r2 & 15;
        const int d = colD;
        const int vcolp = (d & 7) * 8 - 2;
        const int rbase = (d >> 3) * 8 - 2;
        const float* srcp = qkvB + (64 + h * 16) * PIX;
        union { ushort_t us[8]; bf16x8 b; } o8;
        #pragma unroll
        for (int j2 = 0; j2 < 8; ++j2) {
            const int m = i * 32 + half * 16 + rl * 4 + (j2 & 3) + 8 * (j2 >> 2);
            const int cc = m / 576;  const int r3 = m - cc * 576;
            const int orr = r3 / 48; const int r4 = r3 - orr * 48;
            const int oc = r4 >> 2, wg = r4 & 3;
            const int row  = wg * 16 + rbase + orr;
            const int colp = vcolp + oc;
            const bool ok = ((unsigned)row < 64u) && ((unsigned)colp < 64u);
            const float v = ok ? srcp[cc * PIX + row * 64 + colp] : 0.f;
            o8.us[j2] = (ushort_t)(__float_as_uint(v) >> 16);
        }
        *(bf16x8*)&VF[(h * 288 + i) * 512 + half * 256 + (rl * 16 + colD) * 8] = o8.b;
    }
}

// ---------------- K3: MFMA attention, 64 q/wave, ksplit=16, den-in-MFMA ----------------
// grid 512 x 512 (8 waves). bid: x=bid&7 -> h=x>>1, tileLSB=x&1; g=bid>>3: ksbit=g&1, tileHi=g>>1.
__global__ __launch_bounds__(512)
void k_attn(const ushort_t* __restrict__ QH, const ushort_t* __restrict__ QL,
            const ushort_t* __restrict__ KF, const ushort_t* __restrict__ VF,
            float* __restrict__ APart)
{
    const int tid = threadIdx.x;
    const int w   = tid >> 6;
    const int l   = tid & 63;
    const int col = l & 31;
    const int rl  = l >> 5;

    const int bid  = blockIdx.x;
    const int x    = bid & 7;
    const int h    = x >> 1;
    const int g    = bid >> 3;
    const int tile = ((g >> 1) << 1) | (x & 1);     // 0..63, 64 queries each
    const int ks   = w + 8 * (g & 1);               // 0..15
    const int qbase = tile * 64;

    const ushort_t* Qb  = QH + ((h << 12) + qbase + col) * 16 + rl * 8;
    const ushort_t* Qb2 = QL + ((h << 12) + qbase + col) * 16 + rl * 8;
    const bf16x8 qh0 = *(const bf16x8*)&Qb[0];
    const bf16x8 qh1 = *(const bf16x8*)&Qb[512];
    const bf16x8 ql0 = *(const bf16x8*)&Qb2[0];
    const bf16x8 ql1 = *(const bf16x8*)&Qb2[512];

    f32x16 acc0 = {0,0,0,0,0,0,0,0,0,0,0,0,0,0,0,0};
    f32x16 acc1 = {0,0,0,0,0,0,0,0,0,0,0,0,0,0,0,0};
    const f32x16 zero = {0,0,0,0,0,0,0,0,0,0,0,0,0,0,0,0};

    union { uint_t u[4]; bf16x8 b; } vconst;
    const uint_t cfill = (col == 16) ? 0x3F803F80u : 0u;
    vconst.u[0] = cfill; vconst.u[1] = cfill; vconst.u[2] = cfill; vconst.u[3] = cfill;

    const ushort_t* kb = KF + (h * 288 + ks * 18) * 1024;
    const ushort_t* vb = VF + (h * 288 + ks * 18) * 512;

    bf16x8 kh = *(const bf16x8*)&kb[l * 8];
    bf16x8 kl = *(const bf16x8*)&kb[512 + l * 8];
    bf16x8 v0 = vconst.b, v1 = vconst.b;
    if (col < 16) {
        v0 = *(const bf16x8*)&vb[(rl * 16 + col) * 8];
        v1 = *(const bf16x8*)&vb[256 + (rl * 16 + col) * 8];
    }

    for (int i = 0; i < 18; ++i) {
        const bf16x8 ckh = kh, ckl = kl, cv0 = v0, cv1 = v1;
        if (i < 17) {
            kb += 1024; vb += 512;
            kh = *(const bf16x8*)&kb[l * 8];
            kl = *(const bf16x8*)&kb[512 + l * 8];
            if (col < 16) {
                v0 = *(const bf16x8*)&vb[(rl * 16 + col) * 8];
                v1 = *(const bf16x8*)&vb[256 + (rl * 16 + col) * 8];
            }
        }

        f32x16 S0 = __builtin_amdgcn_mfma_f32_32x32x16_bf16(ckh, qh0, zero, 0, 0, 0);
        S0 = __builtin_amdgcn_mfma_f32_32x32x16_bf16(ckl, qh0, S0, 0, 0, 0);
        S0 = __builtin_amdgcn_mfma_f32_32x32x16_bf16(ckh, ql0, S0, 0, 0, 0);
        f32x16 S1 = __builtin_amdgcn_mfma_f32_32x32x16_bf16(ckh, qh1, zero, 0, 0, 0);
        S1 = __builtin_amdgcn_mfma_f32_32x32x16_bf16(ckl, qh1, S1, 0, 0, 0);
        S1 = __builtin_amdgcn_mfma_f32_32x32x16_bf16(ckh, ql1, S1, 0, 0, 0);

        {
            float p[16];
            #pragma unroll
            for (int r = 0; r < 16; ++r) p[r] = EXP2F(S0[r]);
            union { uint_t u[4]; bf16x8 b; } A0, A1;
            #pragma unroll
            for (int j = 0; j < 4; ++j) {
                A0.u[j] = PKHI16(__float_as_uint(p[2 * j + 1]), __float_as_uint(p[2 * j]));
                A1.u[j] = PKHI16(__float_as_uint(p[8 + 2 * j + 1]), __float_as_uint(p[8 + 2 * j]));
            }
            acc0 = __builtin_amdgcn_mfma_f32_32x32x16_bf16(A0.b, cv0, acc0, 0, 0, 0);
            acc0 = __builtin_amdgcn_mfma_f32_32x32x16_bf16(A1.b, cv1, acc0, 0, 0, 0);
        }
        {
            float p[16];
            #pragma unroll
            for (int r = 0; r < 16; ++r) p[r] = EXP2F(S1[r]);
            union { uint_t u[4]; bf16x8 b; } A0, A1;
            #pragma unroll
            for (int j = 0; j < 4; ++j) {
                A0.u[j] = PKHI16(__float_as_uint(p[2 * j + 1]), __float_as_uint(p[2 * j]));
                A1.u[j] = PKHI16(__float_as_uint(p[8 + 2 * j + 1]), __float_as_uint(p[8 + 2 * j]));
            }
            acc1 = __builtin_amdgcn_mfma_f32_32x32x16_bf16(A0.b, cv0, acc1, 0, 0, 0);
            acc1 = __builtin_amdgcn_mfma_f32_32x32x16_bf16(A1.b, cv1, acc1, 0, 0, 0);
        }
    }

    if (col <= 16) {
        float* base = APart + ((size_t)(ks * 4 + h) << 12) * 17;
        #pragma unroll
        for (int j = 0; j < 16; ++j) {
            const int q = qbase + (j & 3) + 8 * (j >> 2) + 4 * rl;
            base[q * 17 + col]        = acc0[j];
            base[(q + 32) * 17 + col] = acc1[j];
        }
    }
}

// ---------------- K4: partial combine (16-way) + divide + output projection ----------------
__global__ __launch_bounds__(256)
void k_proj(const float* __restrict__ APart, const float* __restrict__ w_out,
            float* __restrict__ out)
{
    __shared__ float asum[16 * 72];
    __shared__ float wo[64 * 68];
    __shared__ float as2[16 * 68];
    __shared__ float rdn[64];
    const int tid = threadIdx.x;
    const int pbase = blockIdx.x * 16;

    for (int idx = tid; idx < 1088; idx += 256) {
        int q_l = idx / 68; int rem = idx - q_l * 68;
        int h = rem / 17;  int c17 = rem - h * 17;
        float s = 0.f;
        #pragma unroll
        for (int ks = 0; ks < 16; ++ks)
            s += APart[((size_t)((ks * 4 + h) * PIX + pbase + q_l)) * 17 + c17];
        asum[q_l * 72 + h * 17 + c17] = s;
    }
    for (int idx = tid; idx < 4096; idx += 256)
        wo[(idx >> 6) * 68 + (idx & 63)] = w_out[idx];
    __syncthreads();
    if (tid < 64) {
        int h = tid >> 4, px = tid & 15;
        rdn[tid] = 1.0f / asum[px * 72 + h * 17 + 16];
    }
    __syncthreads();
    for (int idx = tid; idx < 1024; idx += 256) {
        int px = idx >> 6, ii = idx & 63;
        int h = ii >> 4, d = ii & 15;
        as2[px * 68 + ii] = asum[px * 72 + h * 17 + d] * rdn[h * 16 + px];
    }
    __syncthreads();

    const int pl = tid & 15;
    const int og = tid >> 4;
    float a0 = 0.f, a1 = 0.f, a2 = 0.f, a3 = 0.f;
    for (int c = 0; c < 64; c += 4) {
        const float4 xv = *(const float4*)&as2[pl * 68 + c];
        const float4 w0 = *(const float4*)&wo[(og * 4 + 0) * 68 + c];
        const float4 w1 = *(const float4*)&wo[(og * 4 + 1) * 68 + c];
        const float4 w2 = *(const float4*)&wo[(og * 4 + 2) * 68 + c];
        const float4 w3 = *(const float4*)&wo[(og * 4 + 3) * 68 + c];
        a0 = fmaf(xv.x, w0.x, fmaf(xv.y, w0.y, fmaf(xv.z, w0.z, fmaf(xv.w, w0.w, a0))));
        a1 = fmaf(xv.x, w1.x, fmaf(xv.y, w1.y, fmaf(xv.z, w1.z, fmaf(xv.w, w1.w, a1))));
        a2 = fmaf(xv.x, w2.x, fmaf(xv.y, w2.y, fmaf(xv.z, w2.z, fmaf(xv.w, w2.w, a2))));
        a3 = fmaf(xv.x, w3.x, fmaf(xv.y, w3.y, fmaf(xv.z, w3.z, fmaf(xv.w, w3.w, a3))));
    }
    out[(og * 4 + 0) * PIX + pbase + pl] = a0;
    out[(og * 4 + 1) * PIX + pbase + pl] = a1;
    out[(og * 4 + 2) * PIX + pbase + pl] = a2;
    out[(og * 4 + 3) * PIX + pbase + pl] = a3;
}

extern "C" void kernel_launch(void* const* d_in, const int* in_sizes, int n_in,
                              void* d_out, int out_size, void* d_ws, size_t ws_size,
                              hipStream_t stream)
{
    const float* x     = (const float*)d_in[0];
    const float* w_qkv = (const float*)d_in[1];
    const float* w_out = (const float*)d_in[2];
    const float* ln_w  = (const float*)d_in[3];
    float* out = (float*)d_out;
    float* ws  = (float*)d_ws;

    float* qkvB  = ws;
    float* APart = ws + OFF_APART;
    ushort_t* U  = (ushort_t*)(ws + OFF_USHORT);
    ushort_t* QH = U + U_QH;
    ushort_t* QL = U + U_QL;
    ushort_t* KF = U + U_KF;
    ushort_t* VF = U + U_VF;

    k_nq      <<<dim3(256), dim3(256), 0, stream>>>(x, w_qkv, ln_w, qkvB, QH, QL);
    k_prep_kv <<<dim3(576), dim3(256), 0, stream>>>(qkvB, KF, VF);
    k_attn    <<<dim3(512), dim3(512), 0, stream>>>(QH, QL, KF, VF, APart);
    k_proj    <<<dim3(256), dim3(256), 0, stream>>>(APart, w_out, out);
}

// Round 10
// 100.572 us; speedup vs baseline: 1.0787x; 1.0787x over previous
//
#include <hip/hip_runtime.h>
#include <math.h>

#define PIX 4096
typedef unsigned short ushort_t;
typedef unsigned int uint_t;
typedef __attribute__((ext_vector_type(8))) short bf16x8;
typedef __attribute__((ext_vector_type(16))) float f32x16;

// ---- ws layout (floats) ----
//   qkvB  [128][4096]          @ 0         (k ch 0..63, v ch 64..127)
//   APart [8ks][4h][4096][17]  @ 524288    (cols 0-15 = PV partial, col16 = den partial)
// ushort region @ float offset 2752512:
//   QH [4][4096][16] @0                  (Q round-to-nearest bf16, QSCALE folded)
//   KF [4][288][1024] @524288            (per chunk: 512 hi + 512 lo, lane-frag order)
//   VF [4][288][512]  @1703936           (per chunk: 2 halves x 256, hi only, frag order)
#define OFF_APART 524288
#define OFF_USHORT 2752512
#define U_QH 0
#define U_KF 524288
#define U_VF 1703936

#define QSCALE 0.36067376022224087f   // 0.25 * log2(e)

#if defined(__has_builtin)
#if __has_builtin(__builtin_amdgcn_exp2f)
#define EXP2F(x) __builtin_amdgcn_exp2f(x)
#endif
#if __has_builtin(__builtin_amdgcn_perm)
#define PKHI16(u1, u0) __builtin_amdgcn_perm((u1), (u0), 0x07060302u)
#endif
#endif
#ifndef EXP2F
#define EXP2F(x) exp2f(x)
#endif
#ifndef PKHI16
#define PKHI16(u1, u0) (((u0) >> 16) | ((u1) & 0xFFFF0000u))
#endif

__device__ __forceinline__ ushort_t rn_bf16(float x) {
    uint_t u = __float_as_uint(x);
    return (ushort_t)((u + 0x7FFFu + ((u >> 16) & 1u)) >> 16);
}

__device__ __forceinline__ void split8(const float* v, bf16x8& H, bf16x8& L) {
    union { uint_t u[4]; bf16x8 b; } hh, ll;
    #pragma unroll
    for (int j = 0; j < 4; ++j) {
        uint_t u0 = __float_as_uint(v[2 * j]), u1 = __float_as_uint(v[2 * j + 1]);
        hh.u[j] = PKHI16(u1, u0);
        float l0 = v[2 * j]     - __uint_as_float(u0 & 0xFFFF0000u);
        float l1 = v[2 * j + 1] - __uint_as_float(u1 & 0xFFFF0000u);
        ll.u[j] = PKHI16(__float_as_uint(l1), __float_as_uint(l0));
    }
    H = hh.b; L = ll.b;
}

// ---------------- K1: fused norm + qkv MFMA projection ----------------
// grid 256 (px-group = bid>>1 of 32 px, o-half = bid&1), block 256 (4 waves; 3 compute)
__global__ __launch_bounds__(256)
void k_nq(const float* __restrict__ x, const float* __restrict__ w_qkv,
          const float* __restrict__ ln_w, float* __restrict__ qkvB,
          ushort_t* __restrict__ QH)
{
    __shared__ float xs[64 * 32];
    __shared__ float red[2][8][32];
    __shared__ float rstd_s[32];
    __shared__ float lw[64];
    __shared__ ushort_t xh[32 * 64];
    __shared__ ushort_t xl[32 * 64];

    const int tid = threadIdx.x;
    const int px = tid & 31, cg = tid >> 5;
    const int pbase = ((int)blockIdx.x >> 1) * 32;
    const int ohalf = blockIdx.x & 1;

    if (tid < 64) lw[tid] = ln_w[tid];
    float s = 0.f, s2 = 0.f;
    #pragma unroll
    for (int cl = 0; cl < 8; ++cl) {
        int c = cg * 8 + cl;
        float v = x[c * PIX + pbase + px];
        xs[c * 32 + px] = v;
        s += v; s2 = fmaf(v, v, s2);
    }
    red[0][cg][px] = s; red[1][cg][px] = s2;
    __syncthreads();
    if (tid < 32) {
        float a = 0.f, b = 0.f;
        #pragma unroll
        for (int gidx = 0; gidx < 8; ++gidx) { a += red[0][gidx][tid]; b += red[1][gidx][tid]; }
        float mean = a * 0.015625f;
        float var  = fmaf(-mean, mean, b * 0.015625f);
        rstd_s[tid] = 1.0f / sqrtf(var + 1e-5f);
    }
    __syncthreads();
    {
        float vals[8];
        const float r = rstd_s[px];
        #pragma unroll
        for (int cl = 0; cl < 8; ++cl) {
            int c = cg * 8 + cl;
            vals[cl] = xs[c * 32 + px] * r * lw[c];
        }
        bf16x8 H, L; split8(vals, H, L);
        const int g = cg ^ (px & 7);
        *(bf16x8*)&xh[px * 64 + g * 8] = H;
        *(bf16x8*)&xl[px * 64 + g * 8] = L;
    }
    __syncthreads();

    const int w = tid >> 6;
    if (w >= 3) return;
    const int l = tid & 63, col = l & 31, rl = l >> 5;
    const int obase = ohalf * 96 + w * 32;

    bf16x8 wh[4], wl[4], xhf[4], xlf[4];
    const float* wrow = w_qkv + (obase + col) * 64;
    #pragma unroll
    for (int s4 = 0; s4 < 4; ++s4) {
        float tmp[8];
        *(float4*)&tmp[0] = *(const float4*)&wrow[s4 * 16 + rl * 8];
        *(float4*)&tmp[4] = *(const float4*)&wrow[s4 * 16 + rl * 8 + 4];
        split8(tmp, wh[s4], wl[s4]);
        const int g = (s4 * 2 + rl) ^ (col & 7);
        xhf[s4] = *(const bf16x8*)&xh[col * 64 + g * 8];
        xlf[s4] = *(const bf16x8*)&xl[col * 64 + g * 8];
    }
    f32x16 acc = {0,0,0,0,0,0,0,0,0,0,0,0,0,0,0,0};
    #pragma unroll
    for (int s4 = 0; s4 < 4; ++s4) {
        acc = __builtin_amdgcn_mfma_f32_32x32x16_bf16(wh[s4], xhf[s4], acc, 0, 0, 0);
        acc = __builtin_amdgcn_mfma_f32_32x32x16_bf16(wl[s4], xhf[s4], acc, 0, 0, 0);
        acc = __builtin_amdgcn_mfma_f32_32x32x16_bf16(wh[s4], xlf[s4], acc, 0, 0, 0);
    }
    const int gpx = pbase + col;
    #pragma unroll
    for (int j = 0; j < 16; ++j) {
        const int o = obase + (j & 3) + 8 * (j >> 2) + 4 * rl;
        if (o < 64) {
            // Q: single round-to-nearest bf16 (unbiased); QSCALE folded
            QH[((o >> 4) * PIX + gpx) * 16 + (o & 15)] = rn_bf16(acc[j] * QSCALE);
        } else {
            qkvB[(o - 64) * PIX + gpx] = acc[j];
        }
    }
}

// ---------------- K2: K (hi/lo) + V (hi) unfold-gather, 8 elems/thread ----------------
__global__ __launch_bounds__(256)
void k_prep_kv(const float* __restrict__ qkvB,
               ushort_t* __restrict__ KF, ushort_t* __restrict__ VF)
{
    const int bid = blockIdx.x;
    const int tid = threadIdx.x;
    if (bid < 288) {
        const int t = bid * 256 + tid;          // < 73728
        const int h = t / 18432; int r = t - h * 18432;
        const int i = r >> 6;   const int l = r & 63;
        const int col = l & 31, rl = l >> 5;
        const int m = i * 32 + col;
        const int cc = m / 576;  const int r3 = m - cc * 576;
        const int orr = r3 / 48; const int r4 = r3 - orr * 48;
        const int oc = r4 >> 2, wg = r4 & 3;
        const int row = wg * 16 + rl * 8 + orr - 2;
        const bool rowOk = (unsigned)row < 64u;
        const float* src = qkvB + (h * 16 + cc) * PIX + row * 64 + (oc - 2);
        float vals[8];
        #pragma unroll
        for (int j = 0; j < 8; ++j) {
            const int colp = j * 8 + oc - 2;
            vals[j] = (rowOk && (unsigned)colp < 64u) ? src[j * 8] : 0.f;
        }
        bf16x8 H, L; split8(vals, H, L);
        const int base = (h * 288 + i) * 1024 + l * 8;
        *(bf16x8*)&KF[base]       = H;
        *(bf16x8*)&KF[base + 512] = L;
    } else {
        const int t = (bid - 288) * 256 + tid;  // < 73728
        const int h = t / 18432; int r = t - h * 18432;
        const int i = r >> 6;   const int r2 = r & 63;
        const int half = r2 >> 5; const int rl = (r2 >> 4) & 1; const int colD = r2 & 15;
        const int d = colD;
        const int vcolp = (d & 7) * 8 - 2;
        const int rbase = (d >> 3) * 8 - 2;
        const float* srcp = qkvB + (64 + h * 16) * PIX;
        union { ushort_t us[8]; bf16x8 b; } o8;
        #pragma unroll
        for (int j2 = 0; j2 < 8; ++j2) {
            const int m = i * 32 + half * 16 + rl * 4 + (j2 & 3) + 8 * (j2 >> 2);
            const int cc = m / 576;  const int r3 = m - cc * 576;
            const int orr = r3 / 48; const int r4 = r3 - orr * 48;
            const int oc = r4 >> 2, wg = r4 & 3;
            const int row  = wg * 16 + rbase + orr;
            const int colp = vcolp + oc;
            const bool ok = ((unsigned)row < 64u) && ((unsigned)colp < 64u);
            const float v = ok ? srcp[cc * PIX + row * 64 + colp] : 0.f;
            o8.us[j2] = (ushort_t)(__float_as_uint(v) >> 16);
        }
        *(bf16x8*)&VF[(h * 288 + i) * 512 + half * 256 + (rl * 16 + colD) * 8] = o8.b;
    }
}

// ---------------- K3: MFMA attention, 64 q/wave, ksplit=8, QK 2-mfma, den-in-MFMA ----------------
// grid 256 x 512 (8 waves = 8 key-splits). bid: x=bid&7 -> h=x>>1, tile LSB=x&1.
__global__ __launch_bounds__(512)
void k_attn(const ushort_t* __restrict__ QH,
            const ushort_t* __restrict__ KF, const ushort_t* __restrict__ VF,
            float* __restrict__ APart)
{
    const int tid = threadIdx.x;
    const int w   = tid >> 6;       // ks = w
    const int l   = tid & 63;
    const int col = l & 31;
    const int rl  = l >> 5;

    const int bid  = blockIdx.x;
    const int x    = bid & 7;
    const int h    = x >> 1;
    const int tile = ((bid >> 3) << 1) | (x & 1);   // 0..63, 64 queries each
    const int qbase = tile * 64;

    const ushort_t* Qb = QH + ((h << 12) + qbase + col) * 16 + rl * 8;
    const bf16x8 qh0 = *(const bf16x8*)&Qb[0];
    const bf16x8 qh1 = *(const bf16x8*)&Qb[512];    // +32 pixels * 16

    f32x16 acc0 = {0,0,0,0,0,0,0,0,0,0,0,0,0,0,0,0};
    f32x16 acc1 = {0,0,0,0,0,0,0,0,0,0,0,0,0,0,0,0};
    const f32x16 zero = {0,0,0,0,0,0,0,0,0,0,0,0,0,0,0,0};

    union { uint_t u[4]; bf16x8 b; } vconst;
    const uint_t cfill = (col == 16) ? 0x3F803F80u : 0u;
    vconst.u[0] = cfill; vconst.u[1] = cfill; vconst.u[2] = cfill; vconst.u[3] = cfill;

    const ushort_t* kb = KF + (h * 288 + w * 36) * 1024;
    const ushort_t* vb = VF + (h * 288 + w * 36) * 512;

    bf16x8 kh = *(const bf16x8*)&kb[l * 8];
    bf16x8 kl = *(const bf16x8*)&kb[512 + l * 8];
    bf16x8 v0 = vconst.b, v1 = vconst.b;
    if (col < 16) {
        v0 = *(const bf16x8*)&vb[(rl * 16 + col) * 8];
        v1 = *(const bf16x8*)&vb[256 + (rl * 16 + col) * 8];
    }

    for (int i = 0; i < 36; ++i) {
        const bf16x8 ckh = kh, ckl = kl, cv0 = v0, cv1 = v1;
        if (i < 35) {
            kb += 1024; vb += 512;
            kh = *(const bf16x8*)&kb[l * 8];
            kl = *(const bf16x8*)&kb[512 + l * 8];
            if (col < 16) {
                v0 = *(const bf16x8*)&vb[(rl * 16 + col) * 8];
                v1 = *(const bf16x8*)&vb[256 + (rl * 16 + col) * 8];
            }
        }

        // QK: K hi/lo exact, Q single RN-bf16 (2 MFMAs per S-frag)
        f32x16 S0 = __builtin_amdgcn_mfma_f32_32x32x16_bf16(ckh, qh0, zero, 0, 0, 0);
        S0 = __builtin_amdgcn_mfma_f32_32x32x16_bf16(ckl, qh0, S0, 0, 0, 0);
        f32x16 S1 = __builtin_amdgcn_mfma_f32_32x32x16_bf16(ckh, qh1, zero, 0, 0, 0);
        S1 = __builtin_amdgcn_mfma_f32_32x32x16_bf16(ckl, qh1, S1, 0, 0, 0);

        {
            float p[16];
            #pragma unroll
            for (int r = 0; r < 16; ++r) p[r] = EXP2F(S0[r]);
            union { uint_t u[4]; bf16x8 b; } A0, A1;
            #pragma unroll
            for (int j = 0; j < 4; ++j) {
                A0.u[j] = PKHI16(__float_as_uint(p[2 * j + 1]), __float_as_uint(p[2 * j]));
                A1.u[j] = PKHI16(__float_as_uint(p[8 + 2 * j + 1]), __float_as_uint(p[8 + 2 * j]));
            }
            acc0 = __builtin_amdgcn_mfma_f32_32x32x16_bf16(A0.b, cv0, acc0, 0, 0, 0);
            acc0 = __builtin_amdgcn_mfma_f32_32x32x16_bf16(A1.b, cv1, acc0, 0, 0, 0);
        }
        {
            float p[16];
            #pragma unroll
            for (int r = 0; r < 16; ++r) p[r] = EXP2F(S1[r]);
            union { uint_t u[4]; bf16x8 b; } A0, A1;
            #pragma unroll
            for (int j = 0; j < 4; ++j) {
                A0.u[j] = PKHI16(__float_as_uint(p[2 * j + 1]), __float_as_uint(p[2 * j]));
                A1.u[j] = PKHI16(__float_as_uint(p[8 + 2 * j + 1]), __float_as_uint(p[8 + 2 * j]));
            }
            acc1 = __builtin_amdgcn_mfma_f32_32x32x16_bf16(A0.b, cv0, acc1, 0, 0, 0);
            acc1 = __builtin_amdgcn_mfma_f32_32x32x16_bf16(A1.b, cv1, acc1, 0, 0, 0);
        }
    }

    if (col <= 16) {
        float* base = APart + ((size_t)(w * 4 + h) << 12) * 17;
        #pragma unroll
        for (int j = 0; j < 16; ++j) {
            const int q = qbase + (j & 3) + 8 * (j >> 2) + 4 * rl;
            base[q * 17 + col]        = acc0[j];
            base[(q + 32) * 17 + col] = acc1[j];
        }
    }
}

// ---------------- K4: partial combine (8-way) + divide + output projection ----------------
__global__ __launch_bounds__(256)
void k_proj(const float* __restrict__ APart, const float* __restrict__ w_out,
            float* __restrict__ out)
{
    __shared__ float asum[16 * 72];
    __shared__ float wo[64 * 68];
    __shared__ float as2[16 * 68];
    __shared__ float rdn[64];
    const int tid = threadIdx.x;
    const int pbase = blockIdx.x * 16;

    for (int idx = tid; idx < 1088; idx += 256) {
        int q_l = idx / 68; int rem = idx - q_l * 68;
        int h = rem / 17;  int c17 = rem - h * 17;
        float s = 0.f;
        #pragma unroll
        for (int ks = 0; ks < 8; ++ks)
            s += APart[((size_t)((ks * 4 + h) * PIX + pbase + q_l)) * 17 + c17];
        asum[q_l * 72 + h * 17 + c17] = s;
    }
    for (int idx = tid; idx < 4096; idx += 256)
        wo[(idx >> 6) * 68 + (idx & 63)] = w_out[idx];
    __syncthreads();
    if (tid < 64) {
        int h = tid >> 4, px = tid & 15;
        rdn[tid] = 1.0f / asum[px * 72 + h * 17 + 16];
    }
    __syncthreads();
    for (int idx = tid; idx < 1024; idx += 256) {
        int px = idx >> 6, ii = idx & 63;
        int h = ii >> 4, d = ii & 15;
        as2[px * 68 + ii] = asum[px * 72 + h * 17 + d] * rdn[h * 16 + px];
    }
    __syncthreads();

    const int pl = tid & 15;
    const int og = tid >> 4;
    float a0 = 0.f, a1 = 0.f, a2 = 0.f, a3 = 0.f;
    for (int c = 0; c < 64; c += 4) {
        const float4 xv = *(const float4*)&as2[pl * 68 + c];
        const float4 w0 = *(const float4*)&wo[(og * 4 + 0) * 68 + c];
        const float4 w1 = *(const float4*)&wo[(og * 4 + 1) * 68 + c];
        const float4 w2 = *(const float4*)&wo[(og * 4 + 2) * 68 + c];
        const float4 w3 = *(const float4*)&wo[(og * 4 + 3) * 68 + c];
        a0 = fmaf(xv.x, w0.x, fmaf(xv.y, w0.y, fmaf(xv.z, w0.z, fmaf(xv.w, w0.w, a0))));
        a1 = fmaf(xv.x, w1.x, fmaf(xv.y, w1.y, fmaf(xv.z, w1.z, fmaf(xv.w, w1.w, a1))));
        a2 = fmaf(xv.x, w2.x, fmaf(xv.y, w2.y, fmaf(xv.z, w2.z, fmaf(xv.w, w2.w, a2))));
        a3 = fmaf(xv.x, w3.x, fmaf(xv.y, w3.y, fmaf(xv.z, w3.z, fmaf(xv.w, w3.w, a3))));
    }
    out[(og * 4 + 0) * PIX + pbase + pl] = a0;
    out[(og * 4 + 1) * PIX + pbase + pl] = a1;
    out[(og * 4 + 2) * PIX + pbase + pl] = a2;
    out[(og * 4 + 3) * PIX + pbase + pl] = a3;
}

extern "C" void kernel_launch(void* const* d_in, const int* in_sizes, int n_in,
                              void* d_out, int out_size, void* d_ws, size_t ws_size,
                              hipStream_t stream)
{
    const float* x     = (const float*)d_in[0];
    const float* w_qkv = (const float*)d_in[1];
    const float* w_out = (const float*)d_in[2];
    const float* ln_w  = (const float*)d_in[3];
    float* out = (float*)d_out;
    float* ws  = (float*)d_ws;

    float* qkvB  = ws;
    float* APart = ws + OFF_APART;
    ushort_t* U  = (ushort_t*)(ws + OFF_USHORT);
    ushort_t* QH = U + U_QH;
    ushort_t* KF = U + U_KF;
    ushort_t* VF = U + U_VF;

    k_nq      <<<dim3(256), dim3(256), 0, stream>>>(x, w_qkv, ln_w, qkvB, QH);
    k_prep_kv <<<dim3(576), dim3(256), 0, stream>>>(qkvB, KF, VF);
    k_attn    <<<dim3(256), dim3(512), 0, stream>>>(QH, KF, VF, APart);
    k_proj    <<<dim3(256), dim3(256), 0, stream>>>(APart, w_out, out);
}

// Round 11
// 96.986 us; speedup vs baseline: 1.1185x; 1.0370x over previous
//
#include <hip/hip_runtime.h>
#include <math.h>

#define PIX 4096
typedef unsigned short ushort_t;
typedef unsigned int uint_t;
typedef __attribute__((ext_vector_type(8))) short bf16x8;
typedef __attribute__((ext_vector_type(16))) float f32x16;

// ---- ws layout (floats) ----
//   qkvB  [128][4096]          @ 0         (k ch 0..63, v ch 64..127)
//   APart [8ks][4h][4096][17]  @ 524288    (cols 0-15 = PV partial, col16 = den partial)
// ushort region @ float offset 2752512:
//   QH [4][4096][16]  @0                 (Q round-to-nearest bf16, QSCALE folded)
//   KF [4][288][512]  @262144            (per chunk: 512 RN-bf16, lane-frag order)
//   VF [4][288][512]  @851968            (per chunk: 2 halves x 256, RN-bf16, frag order)
#define OFF_APART 524288
#define OFF_USHORT 2752512
#define U_QH 0
#define U_KF 262144
#define U_VF 851968

#define QSCALE 0.36067376022224087f   // 0.25 * log2(e)

#if defined(__has_builtin)
#if __has_builtin(__builtin_amdgcn_exp2f)
#define EXP2F(x) __builtin_amdgcn_exp2f(x)
#endif
#if __has_builtin(__builtin_amdgcn_perm)
#define PKHI16(u1, u0) __builtin_amdgcn_perm((u1), (u0), 0x07060302u)
#endif
#endif
#ifndef EXP2F
#define EXP2F(x) exp2f(x)
#endif
#ifndef PKHI16
#define PKHI16(u1, u0) (((u0) >> 16) | ((u1) & 0xFFFF0000u))
#endif

__device__ __forceinline__ ushort_t rn_bf16(float x) {
    uint_t u = __float_as_uint(x);
    return (ushort_t)((u + 0x7FFFu + ((u >> 16) & 1u)) >> 16);
}

__device__ __forceinline__ void split8(const float* v, bf16x8& H, bf16x8& L) {
    union { uint_t u[4]; bf16x8 b; } hh, ll;
    #pragma unroll
    for (int j = 0; j < 4; ++j) {
        uint_t u0 = __float_as_uint(v[2 * j]), u1 = __float_as_uint(v[2 * j + 1]);
        hh.u[j] = PKHI16(u1, u0);
        float l0 = v[2 * j]     - __uint_as_float(u0 & 0xFFFF0000u);
        float l1 = v[2 * j + 1] - __uint_as_float(u1 & 0xFFFF0000u);
        ll.u[j] = PKHI16(__float_as_uint(l1), __float_as_uint(l0));
    }
    H = hh.b; L = ll.b;
}

// ---------------- K1: fused norm + qkv MFMA projection (unchanged, verified) ----------------
// grid 256 (px-group = bid>>1 of 32 px, o-half = bid&1), block 256 (4 waves; 3 compute)
__global__ __launch_bounds__(256)
void k_nq(const float* __restrict__ x, const float* __restrict__ w_qkv,
          const float* __restrict__ ln_w, float* __restrict__ qkvB,
          ushort_t* __restrict__ QH)
{
    __shared__ float xs[64 * 32];
    __shared__ float red[2][8][32];
    __shared__ float rstd_s[32];
    __shared__ float lw[64];
    __shared__ ushort_t xh[32 * 64];
    __shared__ ushort_t xl[32 * 64];

    const int tid = threadIdx.x;
    const int px = tid & 31, cg = tid >> 5;
    const int pbase = ((int)blockIdx.x >> 1) * 32;
    const int ohalf = blockIdx.x & 1;

    if (tid < 64) lw[tid] = ln_w[tid];
    float s = 0.f, s2 = 0.f;
    #pragma unroll
    for (int cl = 0; cl < 8; ++cl) {
        int c = cg * 8 + cl;
        float v = x[c * PIX + pbase + px];
        xs[c * 32 + px] = v;
        s += v; s2 = fmaf(v, v, s2);
    }
    red[0][cg][px] = s; red[1][cg][px] = s2;
    __syncthreads();
    if (tid < 32) {
        float a = 0.f, b = 0.f;
        #pragma unroll
        for (int gidx = 0; gidx < 8; ++gidx) { a += red[0][gidx][tid]; b += red[1][gidx][tid]; }
        float mean = a * 0.015625f;
        float var  = fmaf(-mean, mean, b * 0.015625f);
        rstd_s[tid] = 1.0f / sqrtf(var + 1e-5f);
    }
    __syncthreads();
    {
        float vals[8];
        const float r = rstd_s[px];
        #pragma unroll
        for (int cl = 0; cl < 8; ++cl) {
            int c = cg * 8 + cl;
            vals[cl] = xs[c * 32 + px] * r * lw[c];
        }
        bf16x8 H, L; split8(vals, H, L);
        const int g = cg ^ (px & 7);
        *(bf16x8*)&xh[px * 64 + g * 8] = H;
        *(bf16x8*)&xl[px * 64 + g * 8] = L;
    }
    __syncthreads();

    const int w = tid >> 6;
    if (w >= 3) return;
    const int l = tid & 63, col = l & 31, rl = l >> 5;
    const int obase = ohalf * 96 + w * 32;

    bf16x8 wh[4], wl[4], xhf[4], xlf[4];
    const float* wrow = w_qkv + (obase + col) * 64;
    #pragma unroll
    for (int s4 = 0; s4 < 4; ++s4) {
        float tmp[8];
        *(float4*)&tmp[0] = *(const float4*)&wrow[s4 * 16 + rl * 8];
        *(float4*)&tmp[4] = *(const float4*)&wrow[s4 * 16 + rl * 8 + 4];
        split8(tmp, wh[s4], wl[s4]);
        const int g = (s4 * 2 + rl) ^ (col & 7);
        xhf[s4] = *(const bf16x8*)&xh[col * 64 + g * 8];
        xlf[s4] = *(const bf16x8*)&xl[col * 64 + g * 8];
    }
    f32x16 acc = {0,0,0,0,0,0,0,0,0,0,0,0,0,0,0,0};
    #pragma unroll
    for (int s4 = 0; s4 < 4; ++s4) {
        acc = __builtin_amdgcn_mfma_f32_32x32x16_bf16(wh[s4], xhf[s4], acc, 0, 0, 0);
        acc = __builtin_amdgcn_mfma_f32_32x32x16_bf16(wl[s4], xhf[s4], acc, 0, 0, 0);
        acc = __builtin_amdgcn_mfma_f32_32x32x16_bf16(wh[s4], xlf[s4], acc, 0, 0, 0);
    }
    const int gpx = pbase + col;
    #pragma unroll
    for (int j = 0; j < 16; ++j) {
        const int o = obase + (j & 3) + 8 * (j >> 2) + 4 * rl;
        if (o < 64) {
            QH[((o >> 4) * PIX + gpx) * 16 + (o & 15)] = rn_bf16(acc[j] * QSCALE);
        } else {
            qkvB[(o - 64) * PIX + gpx] = acc[j];
        }
    }
}

// ---------------- K2: K + V unfold-gather, RN-bf16, 8 elems/thread ----------------
// grid 576 x 256: blocks [0,288) = K rows, [288,576) = V rows
__global__ __launch_bounds__(256)
void k_prep_kv(const float* __restrict__ qkvB,
               ushort_t* __restrict__ KF, ushort_t* __restrict__ VF)
{
    const int bid = blockIdx.x;
    const int tid = threadIdx.x;
    if (bid < 288) {
        const int t = bid * 256 + tid;          // < 73728
        const int h = t / 18432; int r = t - h * 18432;
        const int i = r >> 6;   const int l = r & 63;
        const int col = l & 31, rl = l >> 5;
        const int m = i * 32 + col;
        const int cc = m / 576;  const int r3 = m - cc * 576;
        const int orr = r3 / 48; const int r4 = r3 - orr * 48;
        const int oc = r4 >> 2, wg = r4 & 3;
        const int row = wg * 16 + rl * 8 + orr - 2;
        const bool rowOk = (unsigned)row < 64u;
        const float* src = qkvB + (h * 16 + cc) * PIX + row * 64 + (oc - 2);
        union { ushort_t us[8]; bf16x8 b; } o8;
        #pragma unroll
        for (int j = 0; j < 8; ++j) {
            const int colp = j * 8 + oc - 2;
            const float v = (rowOk && (unsigned)colp < 64u) ? src[j * 8] : 0.f;
            o8.us[j] = rn_bf16(v);
        }
        *(bf16x8*)&KF[(h * 288 + i) * 512 + l * 8] = o8.b;
    } else {
        const int t = (bid - 288) * 256 + tid;  // < 73728
        const int h = t / 18432; int r = t - h * 18432;
        const int i = r >> 6;   const int r2 = r & 63;
        const int half = r2 >> 5; const int rl = (r2 >> 4) & 1; const int colD = r2 & 15;
        const int d = colD;
        const int vcolp = (d & 7) * 8 - 2;
        const int rbase = (d >> 3) * 8 - 2;
        const float* srcp = qkvB + (64 + h * 16) * PIX;
        union { ushort_t us[8]; bf16x8 b; } o8;
        #pragma unroll
        for (int j2 = 0; j2 < 8; ++j2) {
            const int m = i * 32 + half * 16 + rl * 4 + (j2 & 3) + 8 * (j2 >> 2);
            const int cc = m / 576;  const int r3 = m - cc * 576;
            const int orr = r3 / 48; const int r4 = r3 - orr * 48;
            const int oc = r4 >> 2, wg = r4 & 3;
            const int row  = wg * 16 + rbase + orr;
            const int colp = vcolp + oc;
            const bool ok = ((unsigned)row < 64u) && ((unsigned)colp < 64u);
            const float v = ok ? srcp[cc * PIX + row * 64 + colp] : 0.f;
            o8.us[j2] = rn_bf16(v);
        }
        *(bf16x8*)&VF[(h * 288 + i) * 512 + half * 256 + (rl * 16 + colD) * 8] = o8.b;
    }
}

// ---------------- K3: MFMA attention, 64 q/wave, ksplit=8, QK 1-mfma, den-in-MFMA ----------------
// grid 256 x 512 (8 waves = 8 key-splits). bid: x=bid&7 -> h=x>>1, tile LSB=x&1.
__global__ __launch_bounds__(512)
void k_attn(const ushort_t* __restrict__ QH,
            const ushort_t* __restrict__ KF, const ushort_t* __restrict__ VF,
            float* __restrict__ APart)
{
    const int tid = threadIdx.x;
    const int w   = tid >> 6;       // ks = w
    const int l   = tid & 63;
    const int col = l & 31;
    const int rl  = l >> 5;

    const int bid  = blockIdx.x;
    const int x    = bid & 7;
    const int h    = x >> 1;
    const int tile = ((bid >> 3) << 1) | (x & 1);   // 0..63, 64 queries each
    const int qbase = tile * 64;

    const ushort_t* Qb = QH + ((h << 12) + qbase + col) * 16 + rl * 8;
    const bf16x8 qh0 = *(const bf16x8*)&Qb[0];
    const bf16x8 qh1 = *(const bf16x8*)&Qb[512];    // +32 pixels * 16

    f32x16 acc0 = {0,0,0,0,0,0,0,0,0,0,0,0,0,0,0,0};
    f32x16 acc1 = {0,0,0,0,0,0,0,0,0,0,0,0,0,0,0,0};
    const f32x16 zero = {0,0,0,0,0,0,0,0,0,0,0,0,0,0,0,0};

    union { uint_t u[4]; bf16x8 b; } vconst;
    const uint_t cfill = (col == 16) ? 0x3F803F80u : 0u;
    vconst.u[0] = cfill; vconst.u[1] = cfill; vconst.u[2] = cfill; vconst.u[3] = cfill;

    const ushort_t* kb = KF + (h * 288 + w * 36) * 512;
    const ushort_t* vb = VF + (h * 288 + w * 36) * 512;

    bf16x8 kh = *(const bf16x8*)&kb[l * 8];
    bf16x8 v0 = vconst.b, v1 = vconst.b;
    if (col < 16) {
        v0 = *(const bf16x8*)&vb[(rl * 16 + col) * 8];
        v1 = *(const bf16x8*)&vb[256 + (rl * 16 + col) * 8];
    }

    for (int i = 0; i < 36; ++i) {
        const bf16x8 ckh = kh, cv0 = v0, cv1 = v1;
        if (i < 35) {
            kb += 512; vb += 512;
            kh = *(const bf16x8*)&kb[l * 8];
            if (col < 16) {
                v0 = *(const bf16x8*)&vb[(rl * 16 + col) * 8];
                v1 = *(const bf16x8*)&vb[256 + (rl * 16 + col) * 8];
            }
        }

        // QK: K RN-bf16 x Q RN-bf16 (1 MFMA per S-frag)
        f32x16 S0 = __builtin_amdgcn_mfma_f32_32x32x16_bf16(ckh, qh0, zero, 0, 0, 0);
        f32x16 S1 = __builtin_amdgcn_mfma_f32_32x32x16_bf16(ckh, qh1, zero, 0, 0, 0);

        {
            float p[16];
            #pragma unroll
            for (int r = 0; r < 16; ++r) p[r] = EXP2F(S0[r]);
            union { uint_t u[4]; bf16x8 b; } A0, A1;
            #pragma unroll
            for (int j = 0; j < 4; ++j) {
                A0.u[j] = PKHI16(__float_as_uint(p[2 * j + 1]), __float_as_uint(p[2 * j]));
                A1.u[j] = PKHI16(__float_as_uint(p[8 + 2 * j + 1]), __float_as_uint(p[8 + 2 * j]));
            }
            acc0 = __builtin_amdgcn_mfma_f32_32x32x16_bf16(A0.b, cv0, acc0, 0, 0, 0);
            acc0 = __builtin_amdgcn_mfma_f32_32x32x16_bf16(A1.b, cv1, acc0, 0, 0, 0);
        }
        {
            float p[16];
            #pragma unroll
            for (int r = 0; r < 16; ++r) p[r] = EXP2F(S1[r]);
            union { uint_t u[4]; bf16x8 b; } A0, A1;
            #pragma unroll
            for (int j = 0; j < 4; ++j) {
                A0.u[j] = PKHI16(__float_as_uint(p[2 * j + 1]), __float_as_uint(p[2 * j]));
                A1.u[j] = PKHI16(__float_as_uint(p[8 + 2 * j + 1]), __float_as_uint(p[8 + 2 * j]));
            }
            acc1 = __builtin_amdgcn_mfma_f32_32x32x16_bf16(A0.b, cv0, acc1, 0, 0, 0);
            acc1 = __builtin_amdgcn_mfma_f32_32x32x16_bf16(A1.b, cv1, acc1, 0, 0, 0);
        }
    }

    if (col <= 16) {
        float* base = APart + ((size_t)(w * 4 + h) << 12) * 17;
        #pragma unroll
        for (int j = 0; j < 16; ++j) {
            const int q = qbase + (j & 3) + 8 * (j >> 2) + 4 * rl;
            base[q * 17 + col]        = acc0[j];
            base[(q + 32) * 17 + col] = acc1[j];
        }
    }
}

// ---------------- K4: partial combine (8-way) + divide + output projection ----------------
__global__ __launch_bounds__(256)
void k_proj(const float* __restrict__ APart, const float* __restrict__ w_out,
            float* __restrict__ out)
{
    __shared__ float asum[16 * 72];
    __shared__ float wo[64 * 68];
    __shared__ float as2[16 * 68];
    __shared__ float rdn[64];
    const int tid = threadIdx.x;
    const int pbase = blockIdx.x * 16;

    for (int idx = tid; idx < 1088; idx += 256) {
        int q_l = idx / 68; int rem = idx - q_l * 68;
        int h = rem / 17;  int c17 = rem - h * 17;
        float s = 0.f;
        #pragma unroll
        for (int ks = 0; ks < 8; ++ks)
            s += APart[((size_t)((ks * 4 + h) * PIX + pbase + q_l)) * 17 + c17];
        asum[q_l * 72 + h * 17 + c17] = s;
    }
    for (int idx = tid; idx < 4096; idx += 256)
        wo[(idx >> 6) * 68 + (idx & 63)] = w_out[idx];
    __syncthreads();
    if (tid < 64) {
        int h = tid >> 4, px = tid & 15;
        rdn[tid] = 1.0f / asum[px * 72 + h * 17 + 16];
    }
    __syncthreads();
    for (int idx = tid; idx < 1024; idx += 256) {
        int px = idx >> 6, ii = idx & 63;
        int h = ii >> 4, d = ii & 15;
        as2[px * 68 + ii] = asum[px * 72 + h * 17 + d] * rdn[h * 16 + px];
    }
    __syncthreads();

    const int pl = tid & 15;
    const int og = tid >> 4;
    float a0 = 0.f, a1 = 0.f, a2 = 0.f, a3 = 0.f;
    for (int c = 0; c < 64; c += 4) {
        const float4 xv = *(const float4*)&as2[pl * 68 + c];
        const float4 w0 = *(const float4*)&wo[(og * 4 + 0) * 68 + c];
        const float4 w1 = *(const float4*)&wo[(og * 4 + 1) * 68 + c];
        const float4 w2 = *(const float4*)&wo[(og * 4 + 2) * 68 + c];
        const float4 w3 = *(const float4*)&wo[(og * 4 + 3) * 68 + c];
        a0 = fmaf(xv.x, w0.x, fmaf(xv.y, w0.y, fmaf(xv.z, w0.z, fmaf(xv.w, w0.w, a0))));
        a1 = fmaf(xv.x, w1.x, fmaf(xv.y, w1.y, fmaf(xv.z, w1.z, fmaf(xv.w, w1.w, a1))));
        a2 = fmaf(xv.x, w2.x, fmaf(xv.y, w2.y, fmaf(xv.z, w2.z, fmaf(xv.w, w2.w, a2))));
        a3 = fmaf(xv.x, w3.x, fmaf(xv.y, w3.y, fmaf(xv.z, w3.z, fmaf(xv.w, w3.w, a3))));
    }
    out[(og * 4 + 0) * PIX + pbase + pl] = a0;
    out[(og * 4 + 1) * PIX + pbase + pl] = a1;
    out[(og * 4 + 2) * PIX + pbase + pl] = a2;
    out[(og * 4 + 3) * PIX + pbase + pl] = a3;
}

extern "C" void kernel_launch(void* const* d_in, const int* in_sizes, int n_in,
                              void* d_out, int out_size, void* d_ws, size_t ws_size,
                              hipStream_t stream)
{
    const float* x     = (const float*)d_in[0];
    const float* w_qkv = (const float*)d_in[1];
    const float* w_out = (const float*)d_in[2];
    const float* ln_w  = (const float*)d_in[3];
    float* out = (float*)d_out;
    float* ws  = (float*)d_ws;

    float* qkvB  = ws;
    float* APart = ws + OFF_APART;
    ushort_t* U  = (ushort_t*)(ws + OFF_USHORT);
    ushort_t* QH = U + U_QH;
    ushort_t* KF = U + U_KF;
    ushort_t* VF = U + U_VF;

    k_nq      <<<dim3(256), dim3(256), 0, stream>>>(x, w_qkv, ln_w, qkvB, QH);
    k_prep_kv <<<dim3(576), dim3(256), 0, stream>>>(qkvB, KF, VF);
    k_attn    <<<dim3(256), dim3(512), 0, stream>>>(QH, KF, VF, APart);
    k_proj    <<<dim3(256), dim3(256), 0, stream>>>(APart, w_out, out);
}